// Round 1
// baseline (117.648 us; speedup 1.0000x reference)
//
#include <hip/hip_runtime.h>
#include <hip/hip_bf16.h>

// LRU model: logits = relu(T1[q] + sum_s T2[t_s]) @ W2^T + b2
// T1/T2 are 64x64 precomputed tables (vocab=64), padded to stride 68 floats
// to break LDS bank alignment (row start bank = 4*t mod 32).

#define TSTRIDE 68
#define T2_OFF  (64 * TSTRIDE)        // 4352 words
#define LDS_WORDS (2 * 64 * TSTRIDE)  // 8704 words = 34816 B

typedef __attribute__((ext_vector_type(4))) float f32x4;
typedef __attribute__((ext_vector_type(8))) short bf16x8;

__device__ __forceinline__ unsigned pkbf2(float a, float b) {
  float2 f2; f2.x = a; f2.y = b;
  __hip_bfloat162 h = __float22bfloat162_rn(f2);
  union { __hip_bfloat162 h2; unsigned u; } cv; cv.h2 = h;
  return cv.u;
}

// Build T1 (query half, b1 folded) and T2 (memory half, 1/8 folded).
// grid 128 x 64: block = (half, token-row), thread = output feature j.
__global__ void prep_kernel(const float* __restrict__ embed,
                            const float* __restrict__ W1,
                            const float* __restrict__ b1,
                            float* __restrict__ T) {
  const int t    = blockIdx.x & 63;
  const int half = blockIdx.x >> 6;   // 0 -> T1, 1 -> T2
  const int j    = threadIdx.x;       // 0..63
  const float* wrow = W1 + j * 128 + half * 64;
  const float* erow = embed + t * 64;
  float acc = 0.f;
#pragma unroll
  for (int k = 0; k < 64; ++k) acc += wrow[k] * erow[k];
  const float outv = half ? acc * 0.125f : acc + b1[j];
  T[half * T2_OFF + t * TSTRIDE + j] = outv;
}

// Main kernel: 1024 blocks x 256 threads (4 waves). Each wave does 4
// iterations of 16 elements via one 16x16 MFMA tile row (N=64 -> 4 tiles,
// K=64 -> 2 k-steps). Stage-1 gathers table rows straight into the MFMA
// A-fragment layout: lane (qd = lane>>4, m = lane&15) holds features
// qd*8+j (k-step 0) and 32+qd*8+j (k-step 1) of element b0+m.
__global__ __launch_bounds__(256, 4) void lru_kernel(
    const int*   __restrict__ seqs,
    const int*   __restrict__ qtok,
    const float* __restrict__ W2,
    const float* __restrict__ b2,
    const float* __restrict__ T,
    float*       __restrict__ out) {
  __shared__ __align__(16) float lds[LDS_WORDS];
  const int tid = threadIdx.x;

  // stage tables into LDS (contiguous copy, pads included but never read)
  {
    const f32x4* src = (const f32x4*)T;
    f32x4*       dst = (f32x4*)lds;
#pragma unroll 1
    for (int i = tid; i < LDS_WORDS / 4; i += 256) dst[i] = src[i];
  }

  const int lane = tid & 63;
  const int wv   = tid >> 6;
  const int qd   = lane >> 4;
  const int l15  = lane & 15;

  // B-fragments: B[k][n] = W2[n][k]; lane holds n = nt*16+l15, k = ks*32+qd*8+j
  bf16x8 bfr[4][2];
  f32x4  binit[4];
#pragma unroll
  for (int nt = 0; nt < 4; ++nt) {
    const float* wr = W2 + (nt * 16 + l15) * 64 + qd * 8;
#pragma unroll
    for (int ks = 0; ks < 2; ++ks) {
      f32x4 w0 = *(const f32x4*)(wr + ks * 32);
      f32x4 w1 = *(const f32x4*)(wr + ks * 32 + 4);
      union { bf16x8 s; unsigned u[4]; } ub;
      ub.u[0] = pkbf2(w0[0], w0[1]);
      ub.u[1] = pkbf2(w0[2], w0[3]);
      ub.u[2] = pkbf2(w1[0], w1[1]);
      ub.u[3] = pkbf2(w1[2], w1[3]);
      bfr[nt][ks] = ub.s;
    }
    const float bb = b2[nt * 16 + l15];
    binit[nt][0] = bb; binit[nt][1] = bb; binit[nt][2] = bb; binit[nt][3] = bb;
  }
  __syncthreads();

  const int base = blockIdx.x * 256 + wv * 64;
#pragma unroll 1
  for (int it = 0; it < 4; ++it) {
    const int b0   = base + it * 16;
    const int elem = b0 + l15;

    // tokens: seqs[:,15:23]; aligned int4 loads of cols 12..23
    const int* srow = seqs + elem * 24;
    const int4 c0 = *(const int4*)(srow + 12);
    const int4 c1 = *(const int4*)(srow + 16);
    const int4 c2 = *(const int4*)(srow + 20);
    const int  qt = qtok[elem];
    const int tk[8] = {c0.w, c1.x, c1.y, c1.z, c1.w, c2.x, c2.y, c2.z};

    // h accumulation in A-frag slices (fp32)
    const float* r1 = lds + qt * TSTRIDE + qd * 8;
    f32x4 a0 = *(const f32x4*)(r1);
    f32x4 a1 = *(const f32x4*)(r1 + 4);
    f32x4 a2 = *(const f32x4*)(r1 + 32);
    f32x4 a3 = *(const f32x4*)(r1 + 36);
#pragma unroll
    for (int s = 0; s < 8; ++s) {
      const float* r2 = lds + T2_OFF + tk[s] * TSTRIDE + qd * 8;
      a0 += *(const f32x4*)(r2);
      a1 += *(const f32x4*)(r2 + 4);
      a2 += *(const f32x4*)(r2 + 32);
      a3 += *(const f32x4*)(r2 + 36);
    }
#pragma unroll
    for (int i = 0; i < 4; ++i) {
      a0[i] = fmaxf(a0[i], 0.f);
      a1[i] = fmaxf(a1[i], 0.f);
      a2[i] = fmaxf(a2[i], 0.f);
      a3[i] = fmaxf(a3[i], 0.f);
    }
    union { bf16x8 s; unsigned u[4]; } ua, ub2;
    ua.u[0]  = pkbf2(a0[0], a0[1]);
    ua.u[1]  = pkbf2(a0[2], a0[3]);
    ua.u[2]  = pkbf2(a1[0], a1[1]);
    ua.u[3]  = pkbf2(a1[2], a1[3]);
    ub2.u[0] = pkbf2(a2[0], a2[1]);
    ub2.u[1] = pkbf2(a2[2], a2[3]);
    ub2.u[2] = pkbf2(a3[0], a3[1]);
    ub2.u[3] = pkbf2(a3[2], a3[3]);
    const bf16x8 afA = ua.s, afB = ub2.s;

#pragma unroll
    for (int nt = 0; nt < 4; ++nt) {
      f32x4 acc = binit[nt];
      acc = __builtin_amdgcn_mfma_f32_16x16x32_bf16(afA, bfr[nt][0], acc, 0, 0, 0);
      acc = __builtin_amdgcn_mfma_f32_16x16x32_bf16(afB, bfr[nt][1], acc, 0, 0, 0);
      // D: row m = qd*4 + r, col n = nt*16 + l15
      float* op = out + (size_t)(b0 + qd * 4) * 64 + nt * 16 + l15;
#pragma unroll
      for (int r = 0; r < 4; ++r) op[(size_t)r * 64] = acc[r];
    }
  }
}

extern "C" void kernel_launch(void* const* d_in, const int* in_sizes, int n_in,
                              void* d_out, int out_size, void* d_ws, size_t ws_size,
                              hipStream_t stream) {
  const int*   seqs  = (const int*)d_in[0];
  const int*   qtokp = (const int*)d_in[1];
  const float* embed = (const float*)d_in[2];
  const float* W1    = (const float*)d_in[3];
  const float* b1    = (const float*)d_in[4];
  const float* W2    = (const float*)d_in[5];
  const float* b2    = (const float*)d_in[6];
  float*       outp  = (float*)d_out;
  float*       T     = (float*)d_ws;   // 34816 B of tables

  prep_kernel<<<dim3(128), dim3(64), 0, stream>>>(embed, W1, b1, T);
  lru_kernel<<<dim3(1024), dim3(256), 0, stream>>>(seqs, qtokp, W2, b2, T, outp);
}

// Round 3
// 117.029 us; speedup vs baseline: 1.0053x; 1.0053x over previous
//
#include <hip/hip_runtime.h>
#include <hip/hip_bf16.h>

// logits = relu(T1[q] + sum_s T2[t_s]) @ W2^T + b2, vocab=64 so layer-1 is
// 9 table-row gathers. Tables stored as bf16 in LDS (row stride 144 B =
// 36 dwords) -> half the LDS traffic of fp32 and packed dwords are already
// in MFMA A-fragment byte order.

#define RSTRIDE_W 36                    // dwords per row (32 data + 4 pad)
#define T2_OFF_W  (64 * RSTRIDE_W)      // 2304
#define LDS_DW    (2 * 64 * RSTRIDE_W)  // 4608 dwords = 18432 B

typedef __attribute__((ext_vector_type(4))) float f32x4;
typedef __attribute__((ext_vector_type(8))) short bf16x8;

// round-to-nearest-even fp32 -> bf16 (avoids ROCm 7.2 bf16-header overload
// ambiguity with __float2bfloat16_rn)
__device__ __forceinline__ unsigned short f2bf(float x) {
  union { float f; unsigned u; } c; c.f = x;
  unsigned u = c.u + 0x7fffu + ((c.u >> 16) & 1u);
  return (unsigned short)(u >> 16);
}
__device__ __forceinline__ unsigned pkbf2(float a, float b) {
  return (unsigned)f2bf(a) | ((unsigned)f2bf(b) << 16);
}

// T1 (query half, b1 folded) and T2 (memory half, 1/8 folded), bf16.
// grid 128: block = (half, token). thread j = output feature.
__global__ void prep_kernel(const float* __restrict__ embed,
                            const float* __restrict__ W1,
                            const float* __restrict__ b1,
                            unsigned short* __restrict__ T) {
  const int t    = blockIdx.x & 63;
  const int half = blockIdx.x >> 6;
  const int j    = threadIdx.x;
  const float* wrow = W1 + j * 128 + half * 64;
  const float* erow = embed + t * 64;
  float acc = 0.f;
#pragma unroll
  for (int k = 0; k < 64; ++k) acc += wrow[k] * erow[k];
  const float outv = half ? acc * 0.125f : acc + b1[j];
  T[half * (64 * 2 * RSTRIDE_W) + t * (2 * RSTRIDE_W) + j] = f2bf(outv);
}

// 2048 blocks x 256 threads; each wave: 2 iters x 16 elements (one MFMA
// tile row). Lane (qd=lane>>4, m=lane&15) gathers features qd*8..+7 (ks0)
// and 32+qd*8..+7 (ks1) of its element's 9 table rows as packed bf16,
// accumulates in fp32 via shift/mask unpack, ReLUs, repacks to the MFMA
// A-fragment, then 2 MFMAs per 16-col output tile.
__global__ __launch_bounds__(256, 4) void lru_kernel(
    const int*      __restrict__ seqs,
    const int*      __restrict__ qtok,
    const float*    __restrict__ W2,
    const float*    __restrict__ b2,
    const unsigned* __restrict__ T,
    float*          __restrict__ out) {
  __shared__ __align__(16) unsigned lds[LDS_DW];
  const int tid = threadIdx.x;

  {  // stage tables (1152 uint4 = 4*256 + 128)
    const uint4* src = (const uint4*)T;
    uint4*       dst = (uint4*)lds;
#pragma unroll
    for (int r = 0; r < 4; ++r) dst[tid + r * 256] = src[tid + r * 256];
    if (tid < 128) dst[tid + 1024] = src[tid + 1024];
  }

  const int lane = tid & 63;
  const int wv   = tid >> 6;
  const int qd   = lane >> 4;
  const int l15  = lane & 15;

  // B-fragments from W2 (fp32 global): lane holds n=nt*16+l15, k=ks*32+qd*8+j
  bf16x8 bfr[4][2];
  float  bb[4];
#pragma unroll
  for (int nt = 0; nt < 4; ++nt) {
    const float* wr = W2 + (nt * 16 + l15) * 64 + qd * 8;
#pragma unroll
    for (int ks = 0; ks < 2; ++ks) {
      f32x4 w0 = *(const f32x4*)(wr + ks * 32);
      f32x4 w1 = *(const f32x4*)(wr + ks * 32 + 4);
      union { bf16x8 s; unsigned u[4]; } ub;
      ub.u[0] = pkbf2(w0[0], w0[1]);
      ub.u[1] = pkbf2(w0[2], w0[3]);
      ub.u[2] = pkbf2(w1[0], w1[1]);
      ub.u[3] = pkbf2(w1[2], w1[3]);
      bfr[nt][ks] = ub.s;
    }
    bb[nt] = b2[nt * 16 + l15];
  }
  __syncthreads();

  const int base = blockIdx.x * 128 + wv * 32;
#pragma unroll
  for (int it = 0; it < 2; ++it) {
    const int b0   = base + it * 16;
    const int elem = b0 + l15;

    const int* srow = seqs + elem * 24;
    const int4 c0 = *(const int4*)(srow + 12);
    const int4 c1 = *(const int4*)(srow + 16);
    const int4 c2 = *(const int4*)(srow + 20);
    const int  qt = qtok[elem];
    const int tk[8] = {c0.w, c1.x, c1.y, c1.z, c1.w, c2.x, c2.y, c2.z};

    // fp32 accumulators: [0..3]=ks0 dwords, [4..7]=ks1 dwords (lo/hi pair)
    float alo[8], ahi[8];
    {
      const unsigned* r1 = lds + qt * RSTRIDE_W + qd * 4;
      uint4 d0 = *(const uint4*)(r1);
      uint4 d1 = *(const uint4*)(r1 + 16);
#pragma unroll
      for (int i = 0; i < 4; ++i) {
        alo[i]     = __uint_as_float(d0[i] << 16);
        ahi[i]     = __uint_as_float(d0[i] & 0xffff0000u);
        alo[4 + i] = __uint_as_float(d1[i] << 16);
        ahi[4 + i] = __uint_as_float(d1[i] & 0xffff0000u);
      }
    }
#pragma unroll
    for (int s = 0; s < 8; ++s) {
      const unsigned* r2 = lds + T2_OFF_W + tk[s] * RSTRIDE_W + qd * 4;
      uint4 d0 = *(const uint4*)(r2);
      uint4 d1 = *(const uint4*)(r2 + 16);
#pragma unroll
      for (int i = 0; i < 4; ++i) {
        alo[i]     += __uint_as_float(d0[i] << 16);
        ahi[i]     += __uint_as_float(d0[i] & 0xffff0000u);
        alo[4 + i] += __uint_as_float(d1[i] << 16);
        ahi[4 + i] += __uint_as_float(d1[i] & 0xffff0000u);
      }
    }

    union { bf16x8 s; unsigned u[4]; } ua, ub2;
#pragma unroll
    for (int i = 0; i < 4; ++i) {
      ua.u[i]  = pkbf2(fmaxf(alo[i], 0.f),     fmaxf(ahi[i], 0.f));
      ub2.u[i] = pkbf2(fmaxf(alo[4 + i], 0.f), fmaxf(ahi[4 + i], 0.f));
    }
    const bf16x8 afA = ua.s, afB = ub2.s;

#pragma unroll
    for (int nt = 0; nt < 4; ++nt) {
      f32x4 acc;
      acc[0] = bb[nt]; acc[1] = bb[nt]; acc[2] = bb[nt]; acc[3] = bb[nt];
      acc = __builtin_amdgcn_mfma_f32_16x16x32_bf16(afA, bfr[nt][0], acc, 0, 0, 0);
      acc = __builtin_amdgcn_mfma_f32_16x16x32_bf16(afB, bfr[nt][1], acc, 0, 0, 0);
      float* op = out + (size_t)(b0 + qd * 4) * 64 + nt * 16 + l15;
#pragma unroll
      for (int r = 0; r < 4; ++r) op[(size_t)r * 64] = acc[r];
    }
  }
}

extern "C" void kernel_launch(void* const* d_in, const int* in_sizes, int n_in,
                              void* d_out, int out_size, void* d_ws, size_t ws_size,
                              hipStream_t stream) {
  const int*   seqs  = (const int*)d_in[0];
  const int*   qtokp = (const int*)d_in[1];
  const float* embed = (const float*)d_in[2];
  const float* W1    = (const float*)d_in[3];
  const float* b1    = (const float*)d_in[4];
  const float* W2    = (const float*)d_in[5];
  const float* b2    = (const float*)d_in[6];
  float*       outp  = (float*)d_out;

  prep_kernel<<<dim3(128), dim3(64), 0, stream>>>(embed, W1, b1,
                                                  (unsigned short*)d_ws);
  lru_kernel<<<dim3(2048), dim3(256), 0, stream>>>(seqs, qtokp, W2, b2,
                                                   (const unsigned*)d_ws, outp);
}